// Round 1
// baseline (1600.540 us; speedup 1.0000x reference)
//
#include <hip/hip_runtime.h>

// Problem constants
// B=2, S=2048, E=1024, H=16, D=64; rows = B*S = 4096; 3E = 3072.

#define BM 128
#define BN 128
#define BK 16

// C[M,N] = A[M,K] @ W[K,N] + bias[N]
__global__ __launch_bounds__(256, 2) void gemm_bias_kernel(
    const float* __restrict__ A, const float* __restrict__ W,
    const float* __restrict__ bias, float* __restrict__ C,
    int M, int N, int K)
{
    __shared__ float As[BK][BM + 4];   // transposed A tile; +4 pad keeps 16B align & breaks bank stride
    __shared__ float Bs[BK][BN];
    const int bn = blockIdx.x * BN;
    const int bm = blockIdx.y * BM;
    const int t  = threadIdx.x;
    const int tx = t & 15;     // n-direction thread coord
    const int ty = t >> 4;     // m-direction thread coord

    float acc[8][8];
    #pragma unroll
    for (int r = 0; r < 8; ++r)
        #pragma unroll
        for (int c = 0; c < 8; ++c) acc[r][c] = 0.f;

    for (int k0 = 0; k0 < K; k0 += BK) {
        // A tile: 128 rows x 16 k, float4 along k, scatter-transpose into As[k][m]
        #pragma unroll
        for (int p = 0; p < 2; ++p) {
            int idx4 = t + p * 256;          // 0..511
            int i  = idx4 >> 2;              // row 0..127
            int jj = idx4 & 3;               // k-group 0..3
            float4 v = *(const float4*)&A[(size_t)(bm + i) * K + k0 + jj * 4];
            As[jj * 4 + 0][i] = v.x;
            As[jj * 4 + 1][i] = v.y;
            As[jj * 4 + 2][i] = v.z;
            As[jj * 4 + 3][i] = v.w;
        }
        // B tile: 16 k x 128 n, float4 along n (coalesced both ways)
        #pragma unroll
        for (int p = 0; p < 2; ++p) {
            int idx4 = t + p * 256;
            int i4 = idx4 & 31;              // n-group 0..31
            int j  = idx4 >> 5;              // k 0..15
            float4 v = *(const float4*)&W[(size_t)(k0 + j) * N + bn + i4 * 4];
            *(float4*)&Bs[j][i4 * 4] = v;
        }
        __syncthreads();
        #pragma unroll
        for (int kk = 0; kk < BK; ++kk) {
            float a[8], b[8];
            #pragma unroll
            for (int r = 0; r < 8; ++r) a[r] = As[kk][ty * 8 + r];
            #pragma unroll
            for (int c = 0; c < 8; ++c) b[c] = Bs[kk][tx * 8 + c];
            #pragma unroll
            for (int r = 0; r < 8; ++r)
                #pragma unroll
                for (int c = 0; c < 8; ++c)
                    acc[r][c] = fmaf(a[r], b[c], acc[r][c]);
        }
        __syncthreads();
    }
    #pragma unroll
    for (int r = 0; r < 8; ++r) {
        size_t row = (size_t)(bm + ty * 8 + r) * N + bn;
        #pragma unroll
        for (int c = 0; c < 8; ++c) {
            int n = tx * 8 + c;
            C[row + n] = acc[r][c] + bias[bn + n];
        }
    }
}

// Flash attention, fp32. One block = (b, h, 256 queries). Thread owns one query row.
// qkv layout: [b][s][3*1024], Q at col h*64, K at 1024+h*64, V at 2048+h*64.
#define DH 64
#define KT 64

__global__ __launch_bounds__(256, 1) void flash_kernel(
    const float* __restrict__ qkv, const int* __restrict__ mask,
    float* __restrict__ attn, int S)
{
    __shared__ float Ks[KT][DH];
    __shared__ float Vs[KT][DH];
    __shared__ float Ms[KT];

    const int b  = blockIdx.z;
    const int h  = blockIdx.y;
    const int q0 = blockIdx.x * 256;
    const int t  = threadIdx.x;
    const int q  = q0 + t;
    const int row3 = 3 * 1024;

    const float* qrow = qkv + (size_t)(b * S + q) * row3 + h * DH;
    float qreg[DH];
    #pragma unroll
    for (int d = 0; d < DH; ++d) qreg[d] = qrow[d] * 0.125f;   // 1/sqrt(64)

    float m = -1e30f, l = 0.f;
    float acc[DH];
    #pragma unroll
    for (int d = 0; d < DH; ++d) acc[d] = 0.f;

    for (int k0 = 0; k0 < S; k0 += KT) {
        // stage K,V tiles (fully coalesced: lane = d)
        #pragma unroll
        for (int p = 0; p < 16; ++p) {
            int idx = t + p * 256;           // 0..4095
            int r = idx >> 6, d = idx & 63;
            const float* base = qkv + (size_t)(b * S + k0 + r) * row3 + h * DH + d;
            Ks[r][d] = base[1024];
            Vs[r][d] = base[2048];
        }
        if (t < KT) Ms[t] = mask[b * S + k0 + t] ? 0.f : -1e30f;
        __syncthreads();

        for (int r = 0; r < KT; ++r) {
            float s = 0.f;
            #pragma unroll
            for (int d = 0; d < DH; ++d) s = fmaf(qreg[d], Ks[r][d], s);
            s += Ms[r];
            float mn = fmaxf(m, s);
            if (mn > m) {                    // rare rescale (~log(S) times/row)
                float alpha = __expf(m - mn);
                l *= alpha;
                #pragma unroll
                for (int d = 0; d < DH; ++d) acc[d] *= alpha;
                m = mn;
            }
            float p = __expf(s - mn);
            l += p;
            #pragma unroll
            for (int d = 0; d < DH; ++d) acc[d] = fmaf(p, Vs[r][d], acc[d]);
        }
        __syncthreads();
    }

    float inv = 1.f / l;
    float* orow = attn + (size_t)(b * S + q) * 1024 + h * DH;
    #pragma unroll
    for (int d = 0; d < DH; ++d) orow[d] = acc[d] * inv;
}

extern "C" void kernel_launch(void* const* d_in, const int* in_sizes, int n_in,
                              void* d_out, int out_size, void* d_ws, size_t ws_size,
                              hipStream_t stream) {
    const float* x    = (const float*)d_in[0];   // (2,2048,1024)
    const int*   mask = (const int*)  d_in[1];   // (2,2048)
    const float* Wqkv = (const float*)d_in[2];   // (1024,3072)
    const float* bqkv = (const float*)d_in[3];   // (3072,)
    const float* Wout = (const float*)d_in[4];   // (1024,1024)
    const float* bout = (const float*)d_in[5];   // (1024,)
    float* out = (float*)d_out;                  // (2,2048,1024)

    float* qkv  = (float*)d_ws;                        // 4096*3072 floats = 50.3 MB
    float* attn = qkv + (size_t)4096 * 3072;           // 4096*1024 floats = 16.8 MB

    const int M = 4096, E = 1024, N3 = 3072, S = 2048;

    // 1) qkv = x @ Wqkv + bqkv
    gemm_bias_kernel<<<dim3(N3 / BN, M / BM), dim3(256), 0, stream>>>(
        x, Wqkv, bqkv, qkv, M, N3, E);

    // 2) attention -> attn (B,S,E) already in (b,s,h,d) order
    flash_kernel<<<dim3(S / 256, 16, 2), dim3(256), 0, stream>>>(qkv, mask, attn, S);

    // 3) out = attn @ Wout + bout
    gemm_bias_kernel<<<dim3(E / BN, M / BM), dim3(256), 0, stream>>>(
        attn, Wout, bout, out, M, E, E);
}

// Round 3
// 673.842 us; speedup vs baseline: 2.3752x; 2.3752x over previous
//
#include <hip/hip_runtime.h>

// B=2, S=2048, E=1024, H=16, D=64; rows = B*S = 4096; 3E = 3072.

typedef __attribute__((ext_vector_type(8))) short short8;     // 8 bf16 (A/B frag)
typedef __attribute__((ext_vector_type(4))) float floatx4;    // C/D frag

static __device__ __forceinline__ unsigned short f2bf(float f) {
    unsigned u = __float_as_uint(f);
    u += 0x7fffu + ((u >> 16) & 1u);      // round-to-nearest-even
    return (unsigned short)(u >> 16);
}

// hardware exp2 (v_exp_f32)
static __device__ __forceinline__ float hexp2(float x) {
    return __builtin_amdgcn_exp2f(x);
}

#define BM 128
#define BN 128
#define BK 16

// C[M,N] = A[M,K] @ W[K,N] + bias[N]  (fp32 vector GEMM, unchanged from R1)
__global__ __launch_bounds__(256, 2) void gemm_bias_kernel(
    const float* __restrict__ A, const float* __restrict__ W,
    const float* __restrict__ bias, float* __restrict__ C,
    int M, int N, int K)
{
    __shared__ float As[BK][BM + 4];
    __shared__ float Bs[BK][BN];
    const int bn = blockIdx.x * BN;
    const int bm = blockIdx.y * BM;
    const int t  = threadIdx.x;
    const int tx = t & 15;
    const int ty = t >> 4;

    float acc[8][8];
    #pragma unroll
    for (int r = 0; r < 8; ++r)
        #pragma unroll
        for (int c = 0; c < 8; ++c) acc[r][c] = 0.f;

    for (int k0 = 0; k0 < K; k0 += BK) {
        #pragma unroll
        for (int p = 0; p < 2; ++p) {
            int idx4 = t + p * 256;
            int i  = idx4 >> 2;
            int jj = idx4 & 3;
            float4 v = *(const float4*)&A[(size_t)(bm + i) * K + k0 + jj * 4];
            As[jj * 4 + 0][i] = v.x;
            As[jj * 4 + 1][i] = v.y;
            As[jj * 4 + 2][i] = v.z;
            As[jj * 4 + 3][i] = v.w;
        }
        #pragma unroll
        for (int p = 0; p < 2; ++p) {
            int idx4 = t + p * 256;
            int i4 = idx4 & 31;
            int j  = idx4 >> 5;
            float4 v = *(const float4*)&W[(size_t)(k0 + j) * N + bn + i4 * 4];
            *(float4*)&Bs[j][i4 * 4] = v;
        }
        __syncthreads();
        #pragma unroll
        for (int kk = 0; kk < BK; ++kk) {
            float a[8], b[8];
            #pragma unroll
            for (int r = 0; r < 8; ++r) a[r] = As[kk][ty * 8 + r];
            #pragma unroll
            for (int c = 0; c < 8; ++c) b[c] = Bs[kk][tx * 8 + c];
            #pragma unroll
            for (int r = 0; r < 8; ++r)
                #pragma unroll
                for (int c = 0; c < 8; ++c)
                    acc[r][c] = fmaf(a[r], b[c], acc[r][c]);
        }
        __syncthreads();
    }
    #pragma unroll
    for (int r = 0; r < 8; ++r) {
        size_t row = (size_t)(bm + ty * 8 + r) * N + bn;
        #pragma unroll
        for (int c = 0; c < 8; ++c) {
            int n = tx * 8 + c;
            C[row + n] = acc[r][c] + bias[bn + n];
        }
    }
}

// ---------------- MFMA flash attention ----------------
// Block = 256 thr = 4 waves; each wave owns 32 queries (2 M-tiles of 16).
// Per key-tile (64 keys): stage K->Ks[key][d], V->Vt[d][key] (bf16, padded),
// QK^T via mfma_16x16x32_bf16, online softmax (exp2-domain), P via per-wave
// LDS round-trip (C-layout -> A-layout), PV via mfma into fp32 accumulators.
#define KT 64

__global__ __launch_bounds__(256, 2) void flash_mfma_kernel(
    const float* __restrict__ qkv, const int* __restrict__ mask,
    float* __restrict__ attn, int S)
{
    __shared__ unsigned short Ks[64][72];       // keys x d   (stride 144 B)
    __shared__ unsigned short Vt[64][72];       // d    x key (stride 144 B)
    __shared__ unsigned short Ps[4][16][72];    // per-wave P transpose buffer
    __shared__ float Msk[64];

    const int b    = blockIdx.z;
    const int h    = blockIdx.y;
    const int q0   = blockIdx.x * 128;
    const int t    = threadIdx.x;
    const int wave = t >> 6;
    const int lane = t & 63;
    const int l15  = lane & 15;
    const int quad = lane >> 4;
    const size_t bS = (size_t)b * S;
    const int row3 = 3072;

    // Q fragments: scaled by (1/sqrt(D)) * log2(e) so softmax runs in exp2 domain.
    const float qscale = 0.125f * 1.44269504088896340736f;
    short8 qf[2][2];
    #pragma unroll
    for (int tt = 0; tt < 2; ++tt) {
        int q = q0 + wave * 32 + tt * 16 + l15;
        const float* qp = qkv + (bS + q) * row3 + h * 64;
        #pragma unroll
        for (int kc = 0; kc < 2; ++kc) {
            const float* p4 = qp + kc * 32 + quad * 8;
            float4 a = *(const float4*)p4;
            float4 c = *(const float4*)(p4 + 4);
            short8 f;
            f[0] = (short)f2bf(a.x * qscale); f[1] = (short)f2bf(a.y * qscale);
            f[2] = (short)f2bf(a.z * qscale); f[3] = (short)f2bf(a.w * qscale);
            f[4] = (short)f2bf(c.x * qscale); f[5] = (short)f2bf(c.y * qscale);
            f[6] = (short)f2bf(c.z * qscale); f[7] = (short)f2bf(c.w * qscale);
            qf[tt][kc] = f;
        }
    }

    floatx4 outacc[2][4];
    #pragma unroll
    for (int tt = 0; tt < 2; ++tt)
        #pragma unroll
        for (int dt = 0; dt < 4; ++dt) outacc[tt][dt] = (floatx4){0.f, 0.f, 0.f, 0.f};
    floatx4 mrun[2], lrun[2];
    #pragma unroll
    for (int tt = 0; tt < 2; ++tt) {
        mrun[tt] = (floatx4){-1e30f, -1e30f, -1e30f, -1e30f};
        lrun[tt] = (floatx4){0.f, 0.f, 0.f, 0.f};
    }

    for (int k0 = 0; k0 < S; k0 += KT) {
        // ---- stage K,V tile (fp32 -> bf16) ----
        #pragma unroll
        for (int p = 0; p < 4; ++p) {
            int idx = t + p * 256;            // 0..1023
            int key = idx >> 4;               // 0..63
            int dg  = (idx & 15) * 4;         // 0..60
            const float* kp = qkv + (bS + k0 + key) * row3 + 1024 + h * 64 + dg;
            float4 kv = *(const float4*)kp;
            unsigned short kk[4] = {f2bf(kv.x), f2bf(kv.y), f2bf(kv.z), f2bf(kv.w)};
            *(uint2*)&Ks[key][dg] = *(const uint2*)kk;   // 8B store
            float4 vv = *(const float4*)(kp + 1024);
            Vt[dg + 0][key] = f2bf(vv.x);
            Vt[dg + 1][key] = f2bf(vv.y);
            Vt[dg + 2][key] = f2bf(vv.z);
            Vt[dg + 3][key] = f2bf(vv.w);
        }
        if (t < 64) Msk[t] = mask[bS + k0 + t] ? 0.f : -1e30f;
        __syncthreads();

        // ---- fragment loads (shared across both M-tiles) ----
        short8 kf[2][4], vf[2][4];
        #pragma unroll
        for (int kc = 0; kc < 2; ++kc)
            #pragma unroll
            for (int c = 0; c < 4; ++c) {
                kf[kc][c] = *(const short8*)&Ks[c * 16 + l15][kc * 32 + quad * 8];
                vf[kc][c] = *(const short8*)&Vt[c * 16 + l15][kc * 32 + quad * 8];
            }
        float mc[4];
        #pragma unroll
        for (int c = 0; c < 4; ++c) mc[c] = Msk[c * 16 + l15];

        #pragma unroll
        for (int tt = 0; tt < 2; ++tt) {
            // QK^T: 16 queries x 64 keys
            floatx4 sc[4];
            #pragma unroll
            for (int c = 0; c < 4; ++c) {
                sc[c] = (floatx4){0.f, 0.f, 0.f, 0.f};
                sc[c] = __builtin_amdgcn_mfma_f32_16x16x32_bf16(qf[tt][0], kf[0][c], sc[c], 0, 0, 0);
                sc[c] = __builtin_amdgcn_mfma_f32_16x16x32_bf16(qf[tt][1], kf[1][c], sc[c], 0, 0, 0);
                #pragma unroll
                for (int r = 0; r < 4; ++r) sc[c][r] += mc[c];
            }
            // row max across 64 keys (cols live in the 16-lane group)
            floatx4 rm;
            #pragma unroll
            for (int r = 0; r < 4; ++r)
                rm[r] = fmaxf(fmaxf(sc[0][r], sc[1][r]), fmaxf(sc[2][r], sc[3][r]));
            #pragma unroll
            for (int st = 1; st < 16; st <<= 1)
                #pragma unroll
                for (int r = 0; r < 4; ++r)
                    rm[r] = fmaxf(rm[r], __shfl_xor(rm[r], st));
            floatx4 mnew, alpha;
            #pragma unroll
            for (int r = 0; r < 4; ++r) {
                mnew[r]  = fmaxf(mrun[tt][r], rm[r]);
                alpha[r] = hexp2(mrun[tt][r] - mnew[r]);
                mrun[tt][r] = mnew[r];
            }
            // p = exp2(s - m), row sum, write P (bf16) to per-wave LDS
            floatx4 rs = (floatx4){0.f, 0.f, 0.f, 0.f};
            #pragma unroll
            for (int c = 0; c < 4; ++c) {
                #pragma unroll
                for (int r = 0; r < 4; ++r) {
                    float p = hexp2(sc[c][r] - mnew[r]);
                    rs[r] += p;
                    Ps[wave][quad * 4 + r][c * 16 + l15] = f2bf(p);
                }
            }
            #pragma unroll
            for (int st = 1; st < 16; st <<= 1)
                #pragma unroll
                for (int r = 0; r < 4; ++r)
                    rs[r] += __shfl_xor(rs[r], st);
            #pragma unroll
            for (int r = 0; r < 4; ++r)
                lrun[tt][r] = lrun[tt][r] * alpha[r] + rs[r];
            // rescale accumulators
            #pragma unroll
            for (int dt = 0; dt < 4; ++dt)
                #pragma unroll
                for (int r = 0; r < 4; ++r)
                    outacc[tt][dt][r] *= alpha[r];
            // P: C-layout -> A-layout via LDS (same wave; compiler inserts lgkmcnt)
            short8 pf0 = *(const short8*)&Ps[wave][l15][quad * 8];
            short8 pf1 = *(const short8*)&Ps[wave][l15][32 + quad * 8];
            #pragma unroll
            for (int dt = 0; dt < 4; ++dt) {
                outacc[tt][dt] = __builtin_amdgcn_mfma_f32_16x16x32_bf16(pf0, vf[0][dt], outacc[tt][dt], 0, 0, 0);
                outacc[tt][dt] = __builtin_amdgcn_mfma_f32_16x16x32_bf16(pf1, vf[1][dt], outacc[tt][dt], 0, 0, 0);
            }
        }
        __syncthreads();
    }

    // epilogue: normalize and store
    #pragma unroll
    for (int tt = 0; tt < 2; ++tt) {
        floatx4 inv;
        #pragma unroll
        for (int r = 0; r < 4; ++r) inv[r] = 1.f / lrun[tt][r];
        #pragma unroll
        for (int r = 0; r < 4; ++r) {
            int q = q0 + wave * 32 + tt * 16 + quad * 4 + r;
            float* orow = attn + (bS + q) * 1024 + h * 64;
            #pragma unroll
            for (int dt = 0; dt < 4; ++dt)
                orow[dt * 16 + l15] = outacc[tt][dt][r] * inv[r];
        }
    }
}

extern "C" void kernel_launch(void* const* d_in, const int* in_sizes, int n_in,
                              void* d_out, int out_size, void* d_ws, size_t ws_size,
                              hipStream_t stream) {
    const float* x    = (const float*)d_in[0];
    const int*   mask = (const int*)  d_in[1];
    const float* Wqkv = (const float*)d_in[2];
    const float* bqkv = (const float*)d_in[3];
    const float* Wout = (const float*)d_in[4];
    const float* bout = (const float*)d_in[5];
    float* out = (float*)d_out;

    float* qkv  = (float*)d_ws;
    float* attn = qkv + (size_t)4096 * 3072;

    const int M = 4096, E = 1024, N3 = 3072, S = 2048;

    gemm_bias_kernel<<<dim3(N3 / BN, M / BM), dim3(256), 0, stream>>>(
        x, Wqkv, bqkv, qkv, M, N3, E);

    flash_mfma_kernel<<<dim3(S / 128, 16, 2), dim3(256), 0, stream>>>(
        qkv, mask, attn, S);

    gemm_bias_kernel<<<dim3(E / BN, M / BM), dim3(256), 0, stream>>>(
        attn, Wout, bout, out, M, E, E);
}

// Round 4
// 278.801 us; speedup vs baseline: 5.7408x; 2.4169x over previous
//
#include <hip/hip_runtime.h>

// B=2, S=2048, E=1024, H=16, D=64; rows = B*S = 4096; 3E = 3072.

typedef __attribute__((ext_vector_type(8))) short short8;     // 8 bf16 (A/B frag)
typedef __attribute__((ext_vector_type(4))) float floatx4;    // C/D frag
typedef unsigned short ushort_t;

static __device__ __forceinline__ ushort_t f2bf(float f) {
    unsigned u = __float_as_uint(f);
    u += 0x7fffu + ((u >> 16) & 1u);      // round-to-nearest-even
    return (ushort_t)(u >> 16);
}
static __device__ __forceinline__ float bf2f(ushort_t h) {
    return __uint_as_float(((unsigned)h) << 16);
}
static __device__ __forceinline__ float hexp2(float x) {
    return __builtin_amdgcn_exp2f(x);
}
// async global->LDS, 16B per lane; LDS dest = wave-uniform base + lane*16
static __device__ __forceinline__ void gload16(const void* g, void* l) {
    __builtin_amdgcn_global_load_lds(
        (const __attribute__((address_space(1))) unsigned int*)g,
        (__attribute__((address_space(3))) unsigned int*)l, 16, 0, 0);
}

// ---------------- conversion kernels ----------------
// fp32 -> (hi, lo) bf16 split, elementwise, float4 per thread
__global__ __launch_bounds__(256) void conv_split(const float* __restrict__ in,
                                                  ushort_t* __restrict__ hi,
                                                  ushort_t* __restrict__ lo) {
    int i = blockIdx.x * 256 + threadIdx.x;
    float4 v = ((const float4*)in)[i];
    ushort_t hh[4], ll[4];
    hh[0] = f2bf(v.x); hh[1] = f2bf(v.y); hh[2] = f2bf(v.z); hh[3] = f2bf(v.w);
    ll[0] = f2bf(v.x - bf2f(hh[0])); ll[1] = f2bf(v.y - bf2f(hh[1]));
    ll[2] = f2bf(v.z - bf2f(hh[2])); ll[3] = f2bf(v.w - bf2f(hh[3]));
    ((uint2*)hi)[i] = *(const uint2*)hh;
    ((uint2*)lo)[i] = *(const uint2*)ll;
}

// W[K,N] fp32 -> WT_hi/lo[N,K] bf16 (transpose + split), 32x32 LDS tiles
__global__ __launch_bounds__(256) void conv_split_T(const float* __restrict__ W,
                                                    ushort_t* __restrict__ hiT,
                                                    ushort_t* __restrict__ loT,
                                                    int K, int N) {
    __shared__ float tile[32][33];
    const int nb = blockIdx.x * 32, kb = blockIdx.y * 32;
    const int t = threadIdx.x;
    const int r = t >> 3, c4 = (t & 7) * 4;
    float4 v = *(const float4*)&W[(size_t)(kb + r) * N + nb + c4];
    tile[r][c4 + 0] = v.x; tile[r][c4 + 1] = v.y;
    tile[r][c4 + 2] = v.z; tile[r][c4 + 3] = v.w;
    __syncthreads();
    ushort_t hh[4], ll[4];
    #pragma unroll
    for (int j = 0; j < 4; ++j) {
        float a = tile[c4 + j][r];
        hh[j] = f2bf(a);
        ll[j] = f2bf(a - bf2f(hh[j]));
    }
    size_t o = ((size_t)(nb + r) * K + kb + c4) >> 2;   // uint2 index (4 ushorts)
    ((uint2*)hiT)[o] = *(const uint2*)hh;
    ((uint2*)loT)[o] = *(const uint2*)ll;
}

// ---------------- 3-term split-bf16 MFMA GEMM ----------------
// C_bf16[M,N] = (Ahi+Alo)[M,K] @ (Bhi+Blo)^T[N,K]^T + bias (drop lo*lo)
// 128x128 tile, BK=32, 4 waves (2x2), wave tile 64x64 (4x4 of 16x16x32).
// LDS k-block XOR swizzle: cell (row, kp) holds global (row, kp^(row&3)).
__global__ __launch_bounds__(256, 3) void gemm_split3(
    const ushort_t* __restrict__ Ahi, const ushort_t* __restrict__ Alo,
    const ushort_t* __restrict__ Bhi, const ushort_t* __restrict__ Blo,
    const float* __restrict__ bias, ushort_t* __restrict__ C,
    int M, int N, int K)
{
    __shared__ ushort_t Ah[128][32], Al[128][32], Bh[128][32], Bl[128][32];
    const int bn = blockIdx.x * 128, bm = blockIdx.y * 128;
    const int t = threadIdx.x, w = t >> 6, lane = t & 63;
    const int l15 = lane & 15, quad = lane >> 4;
    const int wm = w >> 1, wn = w & 1;

    // staging: wave w covers tile rows [w*32, w*32+32); lane -> (row, k-part)
    const int srow = w * 32 + (lane >> 2);
    const int skp  = (lane & 3) ^ ((lane >> 2) & 3);     // swizzled global k-part
    const int scol = skp * 8;
    const ushort_t* ga  = Ahi + (size_t)(bm + srow) * K + scol;
    const ushort_t* gal = Alo + (size_t)(bm + srow) * K + scol;
    const ushort_t* gb  = Bhi + (size_t)(bn + srow) * K + scol;
    const ushort_t* gbl = Blo + (size_t)(bn + srow) * K + scol;
    const size_t rstep = (size_t)16 * K;

    const int fcol = ((quad ^ (l15 & 3)) * 8);           // frag read col (deswizzle)

    floatx4 acc[4][4];
    #pragma unroll
    for (int mt = 0; mt < 4; ++mt)
        #pragma unroll
        for (int nt = 0; nt < 4; ++nt) acc[mt][nt] = (floatx4){0.f, 0.f, 0.f, 0.f};

    for (int k0 = 0; k0 < K; k0 += 32) {
        #pragma unroll
        for (int i = 0; i < 2; ++i) {
            gload16(ga  + i * rstep + k0, &Ah[w * 32 + i * 16][0]);
            gload16(gal + i * rstep + k0, &Al[w * 32 + i * 16][0]);
            gload16(gb  + i * rstep + k0, &Bh[w * 32 + i * 16][0]);
            gload16(gbl + i * rstep + k0, &Bl[w * 32 + i * 16][0]);
        }
        __syncthreads();
        short8 ah[4], al[4], bh[4], bl[4];
        #pragma unroll
        for (int x = 0; x < 4; ++x) {
            ah[x] = *(const short8*)&Ah[wm * 64 + x * 16 + l15][fcol];
            al[x] = *(const short8*)&Al[wm * 64 + x * 16 + l15][fcol];
            bh[x] = *(const short8*)&Bh[wn * 64 + x * 16 + l15][fcol];
            bl[x] = *(const short8*)&Bl[wn * 64 + x * 16 + l15][fcol];
        }
        #pragma unroll
        for (int mt = 0; mt < 4; ++mt)
            #pragma unroll
            for (int nt = 0; nt < 4; ++nt) {
                acc[mt][nt] = __builtin_amdgcn_mfma_f32_16x16x32_bf16(ah[mt], bh[nt], acc[mt][nt], 0, 0, 0);
                acc[mt][nt] = __builtin_amdgcn_mfma_f32_16x16x32_bf16(al[mt], bh[nt], acc[mt][nt], 0, 0, 0);
                acc[mt][nt] = __builtin_amdgcn_mfma_f32_16x16x32_bf16(ah[mt], bl[nt], acc[mt][nt], 0, 0, 0);
            }
        __syncthreads();
    }
    #pragma unroll
    for (int mt = 0; mt < 4; ++mt)
        #pragma unroll
        for (int r = 0; r < 4; ++r) {
            size_t row = (size_t)(bm + wm * 64 + mt * 16 + quad * 4 + r) * N;
            #pragma unroll
            for (int nt = 0; nt < 4; ++nt) {
                int col = bn + wn * 64 + nt * 16 + l15;
                C[row + col] = f2bf(acc[mt][nt][r] + bias[col]);
            }
        }
}

// ---------------- plain bf16 MFMA GEMM (fp32 out) ----------------
__global__ __launch_bounds__(256, 3) void gemm_bf16(
    const ushort_t* __restrict__ A, const ushort_t* __restrict__ B,
    const float* __restrict__ bias, float* __restrict__ C,
    int M, int N, int K)
{
    __shared__ ushort_t Ah[128][32], Bh[128][32];
    const int bn = blockIdx.x * 128, bm = blockIdx.y * 128;
    const int t = threadIdx.x, w = t >> 6, lane = t & 63;
    const int l15 = lane & 15, quad = lane >> 4;
    const int wm = w >> 1, wn = w & 1;

    const int srow = w * 32 + (lane >> 2);
    const int skp  = (lane & 3) ^ ((lane >> 2) & 3);
    const int scol = skp * 8;
    const ushort_t* ga = A + (size_t)(bm + srow) * K + scol;
    const ushort_t* gb = B + (size_t)(bn + srow) * K + scol;
    const size_t rstep = (size_t)16 * K;
    const int fcol = ((quad ^ (l15 & 3)) * 8);

    floatx4 acc[4][4];
    #pragma unroll
    for (int mt = 0; mt < 4; ++mt)
        #pragma unroll
        for (int nt = 0; nt < 4; ++nt) acc[mt][nt] = (floatx4){0.f, 0.f, 0.f, 0.f};

    for (int k0 = 0; k0 < K; k0 += 32) {
        #pragma unroll
        for (int i = 0; i < 2; ++i) {
            gload16(ga + i * rstep + k0, &Ah[w * 32 + i * 16][0]);
            gload16(gb + i * rstep + k0, &Bh[w * 32 + i * 16][0]);
        }
        __syncthreads();
        short8 ah[4], bh[4];
        #pragma unroll
        for (int x = 0; x < 4; ++x) {
            ah[x] = *(const short8*)&Ah[wm * 64 + x * 16 + l15][fcol];
            bh[x] = *(const short8*)&Bh[wn * 64 + x * 16 + l15][fcol];
        }
        #pragma unroll
        for (int mt = 0; mt < 4; ++mt)
            #pragma unroll
            for (int nt = 0; nt < 4; ++nt)
                acc[mt][nt] = __builtin_amdgcn_mfma_f32_16x16x32_bf16(ah[mt], bh[nt], acc[mt][nt], 0, 0, 0);
        __syncthreads();
    }
    #pragma unroll
    for (int mt = 0; mt < 4; ++mt)
        #pragma unroll
        for (int r = 0; r < 4; ++r) {
            size_t row = (size_t)(bm + wm * 64 + mt * 16 + quad * 4 + r) * N;
            #pragma unroll
            for (int nt = 0; nt < 4; ++nt) {
                int col = bn + wn * 64 + nt * 16 + l15;
                C[row + col] = acc[mt][nt][r] + bias[col];
            }
        }
}

// ---------------- MFMA flash attention, bf16 qkv, fixed-offset softmax ----
// exp2 domain with constant offset (scores bounded); no running max/rescale.
__global__ __launch_bounds__(256, 2) void flash_bf16(
    const ushort_t* __restrict__ qkv, const int* __restrict__ mask,
    ushort_t* __restrict__ attn, int S)
{
    __shared__ ushort_t Ks[64][72];          // [key][d]
    __shared__ ushort_t Vt[64][72];          // [d][key], key-block XOR swizzled
    __shared__ ushort_t Ps[4][16][72];       // per-wave P transpose buffer
    __shared__ float Madd[64];

    const int b = blockIdx.z, h = blockIdx.y, q0 = blockIdx.x * 128;
    const int t = threadIdx.x, wave = t >> 6, lane = t & 63;
    const int l15 = lane & 15, quad = lane >> 4;
    const size_t bS = (size_t)b * S;
    const float c1  = 0.125f * 1.44269504088896340736f;  // (1/sqrt(D))*log2(e)
    const float OFF = 24.0f;

    short8 qf[2][2];
    #pragma unroll
    for (int tt = 0; tt < 2; ++tt) {
        int q = q0 + wave * 32 + tt * 16 + l15;
        const ushort_t* qp = qkv + (bS + q) * 3072 + h * 64;
        qf[tt][0] = *(const short8*)(qp + quad * 8);
        qf[tt][1] = *(const short8*)(qp + 32 + quad * 8);
    }

    floatx4 outacc[2][4];
    floatx4 lsum[2];
    #pragma unroll
    for (int tt = 0; tt < 2; ++tt) {
        lsum[tt] = (floatx4){0.f, 0.f, 0.f, 0.f};
        #pragma unroll
        for (int dt = 0; dt < 4; ++dt) outacc[tt][dt] = (floatx4){0.f, 0.f, 0.f, 0.f};
    }

    for (int k0 = 0; k0 < S; k0 += 64) {
        #pragma unroll
        for (int p = 0; p < 2; ++p) {
            int idx = t + p * 256;               // 0..511
            int key = idx >> 3;                  // 0..63
            int dg  = (idx & 7) * 8;             // 0..56
            const ushort_t* kp = qkv + (bS + k0 + key) * 3072 + 1024 + h * 64 + dg;
            *(uint4*)&Ks[key][dg] = *(const uint4*)kp;
            ushort_t vtmp[8];
            *(uint4*)vtmp = *(const uint4*)(kp + 1024);
            int kb = key >> 3, kw = key & 7;
            #pragma unroll
            for (int j = 0; j < 8; ++j) {
                int d = dg + j;
                Vt[d][(((kb ^ ((d >> 3) & 7)) << 3) | kw)] = vtmp[j];
            }
        }
        if (t < 64) Madd[t] = (mask[bS + k0 + t] ? 0.f : -1e30f) - OFF;
        __syncthreads();

        short8 kf[2][4], vf[2][4];
        #pragma unroll
        for (int kc = 0; kc < 2; ++kc)
            #pragma unroll
            for (int c = 0; c < 4; ++c) {
                kf[kc][c] = *(const short8*)&Ks[c * 16 + l15][kc * 32 + quad * 8];
                int d = c * 16 + l15;
                int cb = (kc * 4 + quad) ^ ((d >> 3) & 7);
                vf[kc][c] = *(const short8*)&Vt[d][cb * 8];
            }
        float madd_c[4];
        #pragma unroll
        for (int c = 0; c < 4; ++c) madd_c[c] = Madd[c * 16 + l15];

        #pragma unroll
        for (int tt = 0; tt < 2; ++tt) {
            floatx4 sc[4];
            #pragma unroll
            for (int c = 0; c < 4; ++c) {
                sc[c] = (floatx4){0.f, 0.f, 0.f, 0.f};
                sc[c] = __builtin_amdgcn_mfma_f32_16x16x32_bf16(qf[tt][0], kf[0][c], sc[c], 0, 0, 0);
                sc[c] = __builtin_amdgcn_mfma_f32_16x16x32_bf16(qf[tt][1], kf[1][c], sc[c], 0, 0, 0);
            }
            #pragma unroll
            for (int c = 0; c < 4; ++c)
                #pragma unroll
                for (int r = 0; r < 4; ++r) {
                    float p = hexp2(fmaf(sc[c][r], c1, madd_c[c]));
                    lsum[tt][r] += p;
                    Ps[wave][quad * 4 + r][c * 16 + l15] = f2bf(p);
                }
            short8 pf0 = *(const short8*)&Ps[wave][l15][quad * 8];
            short8 pf1 = *(const short8*)&Ps[wave][l15][32 + quad * 8];
            #pragma unroll
            for (int dt = 0; dt < 4; ++dt) {
                outacc[tt][dt] = __builtin_amdgcn_mfma_f32_16x16x32_bf16(pf0, vf[0][dt], outacc[tt][dt], 0, 0, 0);
                outacc[tt][dt] = __builtin_amdgcn_mfma_f32_16x16x32_bf16(pf1, vf[1][dt], outacc[tt][dt], 0, 0, 0);
            }
        }
        __syncthreads();
    }

    // one-time l reduction across the 16-lane col groups
    #pragma unroll
    for (int tt = 0; tt < 2; ++tt)
        #pragma unroll
        for (int st = 1; st < 16; st <<= 1)
            #pragma unroll
            for (int r = 0; r < 4; ++r)
                lsum[tt][r] += __shfl_xor(lsum[tt][r], st);

    #pragma unroll
    for (int tt = 0; tt < 2; ++tt)
        #pragma unroll
        for (int r = 0; r < 4; ++r) {
            float inv = 1.f / lsum[tt][r];
            int q = q0 + wave * 32 + tt * 16 + quad * 4 + r;
            ushort_t* orow = attn + (bS + q) * 1024 + h * 64;
            #pragma unroll
            for (int dt = 0; dt < 4; ++dt)
                orow[dt * 16 + l15] = f2bf(outacc[tt][dt][r] * inv);
        }
}

extern "C" void kernel_launch(void* const* d_in, const int* in_sizes, int n_in,
                              void* d_out, int out_size, void* d_ws, size_t ws_size,
                              hipStream_t stream) {
    const float* x    = (const float*)d_in[0];   // (2,2048,1024)
    const int*   mask = (const int*)  d_in[1];   // (2,2048)
    const float* Wqkv = (const float*)d_in[2];   // (1024,3072)
    const float* bqkv = (const float*)d_in[3];   // (3072,)
    const float* Wout = (const float*)d_in[4];   // (1024,1024)
    const float* bout = (const float*)d_in[5];   // (1024,)
    float* out = (float*)d_out;                  // (2,2048,1024) fp32

    // workspace layout (64 MiB total, same footprint as round 1)
    char* ws = (char*)d_ws;
    ushort_t* xhi   = (ushort_t*)(ws);                         //  8 MB  4096x1024
    ushort_t* xlo   = (ushort_t*)(ws + 8388608);               //  8 MB
    ushort_t* wqhiT = (ushort_t*)(ws + 16777216);              //  6 MB  3072x1024
    ushort_t* wqloT = (ushort_t*)(ws + 23068672);              //  6 MB
    ushort_t* qkvb  = (ushort_t*)(ws + 29360128);              // 24 MB  4096x3072
    ushort_t* attnb = (ushort_t*)(ws + 54525952);              //  8 MB  4096x1024
    ushort_t* wohiT = (ushort_t*)(ws + 62914560);              //  2 MB  1024x1024
    ushort_t* woloT = (ushort_t*)(ws + 65011712);              //  2 MB  (unused by gemm)

    const int M = 4096, E = 1024, N3 = 3072, S = 2048;

    conv_split<<<dim3(M * E / 1024), dim3(256), 0, stream>>>(x, xhi, xlo);
    conv_split_T<<<dim3(N3 / 32, E / 32), dim3(256), 0, stream>>>(Wqkv, wqhiT, wqloT, E, N3);

    gemm_split3<<<dim3(N3 / 128, M / 128), dim3(256), 0, stream>>>(
        xhi, xlo, wqhiT, wqloT, bqkv, qkvb, M, N3, E);

    flash_bf16<<<dim3(S / 128, 16, 2), dim3(256), 0, stream>>>(qkvb, mask, attnb, S);

    conv_split_T<<<dim3(E / 32, E / 32), dim3(256), 0, stream>>>(Wout, wohiT, woloT, E, E);

    gemm_bf16<<<dim3(E / 128, M / 128), dim3(256), 0, stream>>>(
        attnb, wohiT, bout, out, M, E, E);
}

// Round 5
// 251.631 us; speedup vs baseline: 6.3607x; 1.1080x over previous
//
#include <hip/hip_runtime.h>

// B=2, S=2048, E=1024, H=16, D=64; rows = B*S = 4096; 3E = 3072.

typedef __attribute__((ext_vector_type(8))) short short8;     // 8 bf16 (A/B frag)
typedef __attribute__((ext_vector_type(4))) float floatx4;    // C/D frag
typedef unsigned short ushort_t;

static __device__ __forceinline__ ushort_t f2bf(float f) {
    unsigned u = __float_as_uint(f);
    u += 0x7fffu + ((u >> 16) & 1u);      // round-to-nearest-even
    return (ushort_t)(u >> 16);
}
static __device__ __forceinline__ float bf2f(ushort_t h) {
    return __uint_as_float(((unsigned)h) << 16);
}
static __device__ __forceinline__ float hexp2(float x) {
    return __builtin_amdgcn_exp2f(x);
}
// async global->LDS, 16B per lane; LDS dest = wave-uniform base + lane*16
static __device__ __forceinline__ void gload16(const void* g, void* l) {
    __builtin_amdgcn_global_load_lds(
        (const __attribute__((address_space(1))) unsigned int*)g,
        (__attribute__((address_space(3))) unsigned int*)l, 16, 0, 0);
}

// ---------------- conversion kernels ----------------
// fp32 -> (hi, lo) bf16 split, elementwise, float4 per thread
__global__ __launch_bounds__(256) void conv_split(const float* __restrict__ in,
                                                  ushort_t* __restrict__ hi,
                                                  ushort_t* __restrict__ lo) {
    int i = blockIdx.x * 256 + threadIdx.x;
    float4 v = ((const float4*)in)[i];
    ushort_t hh[4], ll[4];
    hh[0] = f2bf(v.x); hh[1] = f2bf(v.y); hh[2] = f2bf(v.z); hh[3] = f2bf(v.w);
    ll[0] = f2bf(v.x - bf2f(hh[0])); ll[1] = f2bf(v.y - bf2f(hh[1]));
    ll[2] = f2bf(v.z - bf2f(hh[2])); ll[3] = f2bf(v.w - bf2f(hh[3]));
    ((uint2*)hi)[i] = *(const uint2*)hh;
    ((uint2*)lo)[i] = *(const uint2*)ll;
}

// W[K,N] fp32 -> WT[N,K] bf16 (transpose, hi only), 32x32 LDS tiles
__global__ __launch_bounds__(256) void conv_T_hi(const float* __restrict__ W,
                                                 ushort_t* __restrict__ hiT,
                                                 int K, int N) {
    __shared__ float tile[32][33];
    const int nb = blockIdx.x * 32, kb = blockIdx.y * 32;
    const int t = threadIdx.x;
    const int r = t >> 3, c4 = (t & 7) * 4;
    float4 v = *(const float4*)&W[(size_t)(kb + r) * N + nb + c4];
    tile[r][c4 + 0] = v.x; tile[r][c4 + 1] = v.y;
    tile[r][c4 + 2] = v.z; tile[r][c4 + 3] = v.w;
    __syncthreads();
    ushort_t hh[4];
    #pragma unroll
    for (int j = 0; j < 4; ++j) hh[j] = f2bf(tile[c4 + j][r]);
    size_t o = ((size_t)(nb + r) * K + kb + c4) >> 2;   // uint2 index (4 ushorts)
    ((uint2*)hiT)[o] = *(const uint2*)hh;
}

// ---------------- 2-term split-bf16 MFMA GEMM ----------------
// C_bf16[M,N] = (Ahi+Alo)[M,K] @ Bhi^T[N,K]^T + bias   (x ~fp32, W bf16)
// 128x128 tile, BK=32, 4 waves (2x2), wave tile 64x64 (4x4 of 16x16x32).
// LDS k-block XOR swizzle: cell (row, kp) holds global (row, kp^(row&3)).
__global__ __launch_bounds__(256, 3) void gemm_split2(
    const ushort_t* __restrict__ Ahi, const ushort_t* __restrict__ Alo,
    const ushort_t* __restrict__ Bhi,
    const float* __restrict__ bias, ushort_t* __restrict__ C,
    int M, int N, int K)
{
    __shared__ ushort_t Ah[128][32], Al[128][32], Bh[128][32];
    const int bn = blockIdx.x * 128, bm = blockIdx.y * 128;
    const int t = threadIdx.x, w = t >> 6, lane = t & 63;
    const int l15 = lane & 15, quad = lane >> 4;
    const int wm = w >> 1, wn = w & 1;

    const int srow = w * 32 + (lane >> 2);
    const int skp  = (lane & 3) ^ ((lane >> 2) & 3);     // swizzled global k-part
    const int scol = skp * 8;
    const ushort_t* ga  = Ahi + (size_t)(bm + srow) * K + scol;
    const ushort_t* gal = Alo + (size_t)(bm + srow) * K + scol;
    const ushort_t* gb  = Bhi + (size_t)(bn + srow) * K + scol;
    const size_t rstep = (size_t)16 * K;

    const int fcol = ((quad ^ (l15 & 3)) * 8);           // frag read col (deswizzle)

    floatx4 acc[4][4];
    #pragma unroll
    for (int mt = 0; mt < 4; ++mt)
        #pragma unroll
        for (int nt = 0; nt < 4; ++nt) acc[mt][nt] = (floatx4){0.f, 0.f, 0.f, 0.f};

    for (int k0 = 0; k0 < K; k0 += 32) {
        #pragma unroll
        for (int i = 0; i < 2; ++i) {
            gload16(ga  + i * rstep + k0, &Ah[w * 32 + i * 16][0]);
            gload16(gal + i * rstep + k0, &Al[w * 32 + i * 16][0]);
            gload16(gb  + i * rstep + k0, &Bh[w * 32 + i * 16][0]);
        }
        __syncthreads();
        short8 ah[4], al[4], bh[4];
        #pragma unroll
        for (int x = 0; x < 4; ++x) {
            ah[x] = *(const short8*)&Ah[wm * 64 + x * 16 + l15][fcol];
            al[x] = *(const short8*)&Al[wm * 64 + x * 16 + l15][fcol];
            bh[x] = *(const short8*)&Bh[wn * 64 + x * 16 + l15][fcol];
        }
        #pragma unroll
        for (int mt = 0; mt < 4; ++mt)
            #pragma unroll
            for (int nt = 0; nt < 4; ++nt) {
                acc[mt][nt] = __builtin_amdgcn_mfma_f32_16x16x32_bf16(ah[mt], bh[nt], acc[mt][nt], 0, 0, 0);
                acc[mt][nt] = __builtin_amdgcn_mfma_f32_16x16x32_bf16(al[mt], bh[nt], acc[mt][nt], 0, 0, 0);
            }
        __syncthreads();
    }
    #pragma unroll
    for (int mt = 0; mt < 4; ++mt)
        #pragma unroll
        for (int r = 0; r < 4; ++r) {
            size_t row = (size_t)(bm + wm * 64 + mt * 16 + quad * 4 + r) * N;
            #pragma unroll
            for (int nt = 0; nt < 4; ++nt) {
                int col = bn + wn * 64 + nt * 16 + l15;
                C[row + col] = f2bf(acc[mt][nt][r] + bias[col]);
            }
        }
}

// ---------------- plain bf16 MFMA GEMM (fp32 out) ----------------
__global__ __launch_bounds__(256, 3) void gemm_bf16(
    const ushort_t* __restrict__ A, const ushort_t* __restrict__ B,
    const float* __restrict__ bias, float* __restrict__ C,
    int M, int N, int K)
{
    __shared__ ushort_t Ah[128][32], Bh[128][32];
    const int bn = blockIdx.x * 128, bm = blockIdx.y * 128;
    const int t = threadIdx.x, w = t >> 6, lane = t & 63;
    const int l15 = lane & 15, quad = lane >> 4;
    const int wm = w >> 1, wn = w & 1;

    const int srow = w * 32 + (lane >> 2);
    const int skp  = (lane & 3) ^ ((lane >> 2) & 3);
    const int scol = skp * 8;
    const ushort_t* ga = A + (size_t)(bm + srow) * K + scol;
    const ushort_t* gb = B + (size_t)(bn + srow) * K + scol;
    const size_t rstep = (size_t)16 * K;
    const int fcol = ((quad ^ (l15 & 3)) * 8);

    floatx4 acc[4][4];
    #pragma unroll
    for (int mt = 0; mt < 4; ++mt)
        #pragma unroll
        for (int nt = 0; nt < 4; ++nt) acc[mt][nt] = (floatx4){0.f, 0.f, 0.f, 0.f};

    for (int k0 = 0; k0 < K; k0 += 32) {
        #pragma unroll
        for (int i = 0; i < 2; ++i) {
            gload16(ga + i * rstep + k0, &Ah[w * 32 + i * 16][0]);
            gload16(gb + i * rstep + k0, &Bh[w * 32 + i * 16][0]);
        }
        __syncthreads();
        short8 ah[4], bh[4];
        #pragma unroll
        for (int x = 0; x < 4; ++x) {
            ah[x] = *(const short8*)&Ah[wm * 64 + x * 16 + l15][fcol];
            bh[x] = *(const short8*)&Bh[wn * 64 + x * 16 + l15][fcol];
        }
        #pragma unroll
        for (int mt = 0; mt < 4; ++mt)
            #pragma unroll
            for (int nt = 0; nt < 4; ++nt)
                acc[mt][nt] = __builtin_amdgcn_mfma_f32_16x16x32_bf16(ah[mt], bh[nt], acc[mt][nt], 0, 0, 0);
        __syncthreads();
    }
    #pragma unroll
    for (int mt = 0; mt < 4; ++mt)
        #pragma unroll
        for (int r = 0; r < 4; ++r) {
            size_t row = (size_t)(bm + wm * 64 + mt * 16 + quad * 4 + r) * N;
            #pragma unroll
            for (int nt = 0; nt < 4; ++nt) {
                int col = bn + wn * 64 + nt * 16 + l15;
                C[row + col] = acc[mt][nt][r] + bias[col];
            }
        }
}

// ---------------- MFMA flash attention, transposed-S formulation ----------
// Scores computed as S^T = mfma(A=K, B=Q): lane holds (key=c*16+quad*4+r, q=l15).
// P^T written as b64 packs to Ps[q][key], read back as b128 B-frags.
// Output computed as out^T = mfma(A=V^T, B=P^T): lane holds (d, q=l15).
__global__ __launch_bounds__(256, 2) void flash_bf16(
    const ushort_t* __restrict__ qkv, const int* __restrict__ mask,
    ushort_t* __restrict__ attn, int S)
{
    __shared__ ushort_t Ks[64][72];          // [key][d]
    __shared__ ushort_t Vt[64][72];          // [d][key], key-block XOR swizzled
    __shared__ ushort_t Ps[4][16][72];       // per-wave P^T: [q(16)][key(64)]
    __shared__ float Madd[64];

    const int b = blockIdx.z, h = blockIdx.y, q0 = blockIdx.x * 128;
    const int t = threadIdx.x, wave = t >> 6, lane = t & 63;
    const int l15 = lane & 15, quad = lane >> 4;
    const size_t bS = (size_t)b * S;
    const float c1  = 0.125f * 1.44269504088896340736f;  // (1/sqrt(D))*log2(e)
    const float OFF = 24.0f;

    short8 qf[2][2];
    #pragma unroll
    for (int tt = 0; tt < 2; ++tt) {
        int q = q0 + wave * 32 + tt * 16 + l15;
        const ushort_t* qp = qkv + (bS + q) * 3072 + h * 64;
        qf[tt][0] = *(const short8*)(qp + quad * 8);
        qf[tt][1] = *(const short8*)(qp + 32 + quad * 8);
    }

    floatx4 outacc[2][4];
    float lsum[2] = {0.f, 0.f};
    #pragma unroll
    for (int tt = 0; tt < 2; ++tt)
        #pragma unroll
        for (int dt = 0; dt < 4; ++dt) outacc[tt][dt] = (floatx4){0.f, 0.f, 0.f, 0.f};

    for (int k0 = 0; k0 < S; k0 += 64) {
        #pragma unroll
        for (int p = 0; p < 2; ++p) {
            int idx = t + p * 256;               // 0..511
            int key = idx >> 3;                  // 0..63
            int dg  = (idx & 7) * 8;             // 0..56
            const ushort_t* kp = qkv + (bS + k0 + key) * 3072 + 1024 + h * 64 + dg;
            *(uint4*)&Ks[key][dg] = *(const uint4*)kp;
            ushort_t vtmp[8];
            *(uint4*)vtmp = *(const uint4*)(kp + 1024);
            int kb = key >> 3, kw = key & 7;
            #pragma unroll
            for (int j = 0; j < 8; ++j) {
                int d = dg + j;
                Vt[d][(((kb ^ ((d >> 3) & 7)) << 3) | kw)] = vtmp[j];
            }
        }
        if (t < 64) Madd[t] = (mask[bS + k0 + t] ? 0.f : -1e30f) - OFF;
        __syncthreads();

        short8 kf[2][4], vf[2][4];
        #pragma unroll
        for (int kc = 0; kc < 2; ++kc)
            #pragma unroll
            for (int c = 0; c < 4; ++c) {
                kf[kc][c] = *(const short8*)&Ks[c * 16 + l15][kc * 32 + quad * 8];
                int d = c * 16 + l15;
                int cb = (kc * 4 + quad) ^ ((d >> 3) & 7);
                vf[kc][c] = *(const short8*)&Vt[d][cb * 8];
            }
        float4 madd4[4];
        #pragma unroll
        for (int c = 0; c < 4; ++c) madd4[c] = *(const float4*)&Madd[c * 16 + quad * 4];

        #pragma unroll
        for (int tt = 0; tt < 2; ++tt) {
            // S^T: lane holds keys c*16+quad*4+r for query q = l15
            floatx4 sc[4];
            #pragma unroll
            for (int c = 0; c < 4; ++c) {
                sc[c] = (floatx4){0.f, 0.f, 0.f, 0.f};
                sc[c] = __builtin_amdgcn_mfma_f32_16x16x32_bf16(kf[0][c], qf[tt][0], sc[c], 0, 0, 0);
                sc[c] = __builtin_amdgcn_mfma_f32_16x16x32_bf16(kf[1][c], qf[tt][1], sc[c], 0, 0, 0);
            }
            // p = exp2(s*c1 + madd); pack consecutive-key pairs; one b64 per c
            #pragma unroll
            for (int c = 0; c < 4; ++c) {
                float p0 = hexp2(fmaf(sc[c][0], c1, madd4[c].x));
                float p1 = hexp2(fmaf(sc[c][1], c1, madd4[c].y));
                float p2 = hexp2(fmaf(sc[c][2], c1, madd4[c].z));
                float p3 = hexp2(fmaf(sc[c][3], c1, madd4[c].w));
                lsum[tt] += (p0 + p1) + (p2 + p3);
                uint2 pk;
                pk.x = (unsigned)f2bf(p0) | ((unsigned)f2bf(p1) << 16);
                pk.y = (unsigned)f2bf(p2) | ((unsigned)f2bf(p3) << 16);
                *(uint2*)&Ps[wave][l15][c * 16 + quad * 4] = pk;
            }
            short8 pf0 = *(const short8*)&Ps[wave][l15][quad * 8];
            short8 pf1 = *(const short8*)&Ps[wave][l15][32 + quad * 8];
            // out^T += V^T * P^T : lane holds (d = dt*16+quad*4+r, q = l15)
            #pragma unroll
            for (int dt = 0; dt < 4; ++dt) {
                outacc[tt][dt] = __builtin_amdgcn_mfma_f32_16x16x32_bf16(vf[0][dt], pf0, outacc[tt][dt], 0, 0, 0);
                outacc[tt][dt] = __builtin_amdgcn_mfma_f32_16x16x32_bf16(vf[1][dt], pf1, outacc[tt][dt], 0, 0, 0);
            }
        }
        __syncthreads();
    }

    // l: sum across the 4 quads (each quad covered a disjoint key subset)
    #pragma unroll
    for (int tt = 0; tt < 2; ++tt) {
        lsum[tt] += __shfl_xor(lsum[tt], 16);
        lsum[tt] += __shfl_xor(lsum[tt], 32);
    }

    #pragma unroll
    for (int tt = 0; tt < 2; ++tt) {
        float inv = 1.f / lsum[tt];
        int q = q0 + wave * 32 + tt * 16 + l15;
        ushort_t* orow = attn + (bS + q) * 1024 + h * 64;
        #pragma unroll
        for (int dt = 0; dt < 4; ++dt) {
            uint2 pk;
            pk.x = (unsigned)f2bf(outacc[tt][dt][0] * inv) |
                   ((unsigned)f2bf(outacc[tt][dt][1] * inv) << 16);
            pk.y = (unsigned)f2bf(outacc[tt][dt][2] * inv) |
                   ((unsigned)f2bf(outacc[tt][dt][3] * inv) << 16);
            *(uint2*)&orow[dt * 16 + quad * 4] = pk;
        }
    }
}

extern "C" void kernel_launch(void* const* d_in, const int* in_sizes, int n_in,
                              void* d_out, int out_size, void* d_ws, size_t ws_size,
                              hipStream_t stream) {
    const float* x    = (const float*)d_in[0];   // (2,2048,1024)
    const int*   mask = (const int*)  d_in[1];   // (2,2048)
    const float* Wqkv = (const float*)d_in[2];   // (1024,3072)
    const float* bqkv = (const float*)d_in[3];   // (3072,)
    const float* Wout = (const float*)d_in[4];   // (1024,1024)
    const float* bout = (const float*)d_in[5];   // (1024,)
    float* out = (float*)d_out;                  // (2,2048,1024) fp32

    char* ws = (char*)d_ws;
    ushort_t* xhi  = (ushort_t*)(ws);                          //  8 MB  4096x1024
    ushort_t* xlo  = (ushort_t*)(ws + 8388608);                //  8 MB
    ushort_t* wqT  = (ushort_t*)(ws + 16777216);               //  6 MB  3072x1024
    ushort_t* qkvb = (ushort_t*)(ws + 23068672);               // 24 MB  4096x3072
    ushort_t* attnb= (ushort_t*)(ws + 48234496);               //  8 MB  4096x1024
    ushort_t* woT  = (ushort_t*)(ws + 56623104);               //  2 MB  1024x1024

    const int M = 4096, E = 1024, N3 = 3072, S = 2048;

    conv_split<<<dim3(M * E / 1024), dim3(256), 0, stream>>>(x, xhi, xlo);
    conv_T_hi<<<dim3(N3 / 32, E / 32), dim3(256), 0, stream>>>(Wqkv, wqT, E, N3);

    gemm_split2<<<dim3(N3 / 128, M / 128), dim3(256), 0, stream>>>(
        xhi, xlo, wqT, bqkv, qkvb, M, N3, E);

    flash_bf16<<<dim3(S / 128, 16, 2), dim3(256), 0, stream>>>(qkvb, mask, attnb, S);

    conv_T_hi<<<dim3(E / 32, E / 32), dim3(256), 0, stream>>>(Wout, woT, E, E);

    gemm_bf16<<<dim3(E / 128, M / 128), dim3(256), 0, stream>>>(
        attnb, woT, bout, out, M, E, E);
}

// Round 6
// 229.497 us; speedup vs baseline: 6.9741x; 1.0964x over previous
//
#include <hip/hip_runtime.h>

// B=2, S=2048, E=1024, H=16, D=64; rows = B*S = 4096; 3E = 3072.

typedef __attribute__((ext_vector_type(8))) short short8;     // 8 bf16 (A/B frag)
typedef __attribute__((ext_vector_type(4))) float floatx4;    // C/D frag
typedef unsigned short ushort_t;

static __device__ __forceinline__ ushort_t f2bf(float f) {
    unsigned u = __float_as_uint(f);
    u += 0x7fffu + ((u >> 16) & 1u);      // round-to-nearest-even
    return (ushort_t)(u >> 16);
}
static __device__ __forceinline__ float bf2f(ushort_t h) {
    return __uint_as_float(((unsigned)h) << 16);
}
static __device__ __forceinline__ float hexp2(float x) {
    return __builtin_amdgcn_exp2f(x);
}
// async global->LDS, 16B per lane; LDS dest = wave-uniform base + lane*16
static __device__ __forceinline__ void gload16(const void* g, void* l) {
    __builtin_amdgcn_global_load_lds(
        (const __attribute__((address_space(1))) unsigned int*)g,
        (__attribute__((address_space(3))) unsigned int*)l, 16, 0, 0);
}

// ---------------- conversion kernels ----------------
// fp32 -> (hi, lo) bf16 split, elementwise, float4 per thread
__global__ __launch_bounds__(256) void conv_split(const float* __restrict__ in,
                                                  ushort_t* __restrict__ hi,
                                                  ushort_t* __restrict__ lo) {
    int i = blockIdx.x * 256 + threadIdx.x;
    float4 v = ((const float4*)in)[i];
    ushort_t hh[4], ll[4];
    hh[0] = f2bf(v.x); hh[1] = f2bf(v.y); hh[2] = f2bf(v.z); hh[3] = f2bf(v.w);
    ll[0] = f2bf(v.x - bf2f(hh[0])); ll[1] = f2bf(v.y - bf2f(hh[1]));
    ll[2] = f2bf(v.z - bf2f(hh[2])); ll[3] = f2bf(v.w - bf2f(hh[3]));
    ((uint2*)hi)[i] = *(const uint2*)hh;
    ((uint2*)lo)[i] = *(const uint2*)ll;
}

// W[K,N] fp32 -> WT[N,K] bf16 (transpose, hi only), 32x32 LDS tiles
__global__ __launch_bounds__(256) void conv_T_hi(const float* __restrict__ W,
                                                 ushort_t* __restrict__ hiT,
                                                 int K, int N) {
    __shared__ float tile[32][33];
    const int nb = blockIdx.x * 32, kb = blockIdx.y * 32;
    const int t = threadIdx.x;
    const int r = t >> 3, c4 = (t & 7) * 4;
    float4 v = *(const float4*)&W[(size_t)(kb + r) * N + nb + c4];
    tile[r][c4 + 0] = v.x; tile[r][c4 + 1] = v.y;
    tile[r][c4 + 2] = v.z; tile[r][c4 + 3] = v.w;
    __syncthreads();
    ushort_t hh[4];
    #pragma unroll
    for (int j = 0; j < 4; ++j) hh[j] = f2bf(tile[c4 + j][r]);
    size_t o = ((size_t)(nb + r) * K + kb + c4) >> 2;   // uint2 index (4 ushorts)
    ((uint2*)hiT)[o] = *(const uint2*)hh;
}

// V part of qkvb -> Vtg[b][h][d][s]  (64x64 tiles through LDS)
__global__ __launch_bounds__(256) void transpose_v(const ushort_t* __restrict__ qkvb,
                                                   ushort_t* __restrict__ vtg) {
    __shared__ ushort_t tile[64][72];
    const int b = blockIdx.z, h = blockIdx.y, s0 = blockIdx.x * 64;
    const int t = threadIdx.x;
    #pragma unroll
    for (int p = 0; p < 2; ++p) {
        int idx = t + p * 256;
        int sl = idx >> 3, dc = (idx & 7) * 8;
        *(uint4*)&tile[sl][dc] =
            *(const uint4*)&qkvb[(size_t)(b * 2048 + s0 + sl) * 3072 + 2048 + h * 64 + dc];
    }
    __syncthreads();
    #pragma unroll
    for (int p = 0; p < 2; ++p) {
        int idx = t + p * 256;
        int dl = idx >> 3, sc = (idx & 7) * 8;
        ushort_t v[8];
        #pragma unroll
        for (int j = 0; j < 8; ++j) v[j] = tile[sc + j][dl];
        *(uint4*)&vtg[(size_t)((b * 16 + h) * 64 + dl) * 2048 + s0 + sc] = *(const uint4*)v;
    }
}

// ---------------- 2-term split-bf16 MFMA GEMM ----------------
__global__ __launch_bounds__(256, 3) void gemm_split2(
    const ushort_t* __restrict__ Ahi, const ushort_t* __restrict__ Alo,
    const ushort_t* __restrict__ Bhi,
    const float* __restrict__ bias, ushort_t* __restrict__ C,
    int M, int N, int K)
{
    __shared__ ushort_t Ah[128][32], Al[128][32], Bh[128][32];
    const int bn = blockIdx.x * 128, bm = blockIdx.y * 128;
    const int t = threadIdx.x, w = t >> 6, lane = t & 63;
    const int l15 = lane & 15, quad = lane >> 4;
    const int wm = w >> 1, wn = w & 1;

    const int srow = w * 32 + (lane >> 2);
    const int skp  = (lane & 3) ^ ((lane >> 2) & 3);     // swizzled global k-part
    const int scol = skp * 8;
    const ushort_t* ga  = Ahi + (size_t)(bm + srow) * K + scol;
    const ushort_t* gal = Alo + (size_t)(bm + srow) * K + scol;
    const ushort_t* gb  = Bhi + (size_t)(bn + srow) * K + scol;
    const size_t rstep = (size_t)16 * K;

    const int fcol = ((quad ^ (l15 & 3)) * 8);           // frag read col (deswizzle)

    floatx4 acc[4][4];
    #pragma unroll
    for (int mt = 0; mt < 4; ++mt)
        #pragma unroll
        for (int nt = 0; nt < 4; ++nt) acc[mt][nt] = (floatx4){0.f, 0.f, 0.f, 0.f};

    for (int k0 = 0; k0 < K; k0 += 32) {
        #pragma unroll
        for (int i = 0; i < 2; ++i) {
            gload16(ga  + i * rstep + k0, &Ah[w * 32 + i * 16][0]);
            gload16(gal + i * rstep + k0, &Al[w * 32 + i * 16][0]);
            gload16(gb  + i * rstep + k0, &Bh[w * 32 + i * 16][0]);
        }
        __syncthreads();
        short8 ah[4], al[4], bh[4];
        #pragma unroll
        for (int x = 0; x < 4; ++x) {
            ah[x] = *(const short8*)&Ah[wm * 64 + x * 16 + l15][fcol];
            al[x] = *(const short8*)&Al[wm * 64 + x * 16 + l15][fcol];
            bh[x] = *(const short8*)&Bh[wn * 64 + x * 16 + l15][fcol];
        }
        #pragma unroll
        for (int mt = 0; mt < 4; ++mt)
            #pragma unroll
            for (int nt = 0; nt < 4; ++nt) {
                acc[mt][nt] = __builtin_amdgcn_mfma_f32_16x16x32_bf16(ah[mt], bh[nt], acc[mt][nt], 0, 0, 0);
                acc[mt][nt] = __builtin_amdgcn_mfma_f32_16x16x32_bf16(al[mt], bh[nt], acc[mt][nt], 0, 0, 0);
            }
        __syncthreads();
    }
    #pragma unroll
    for (int mt = 0; mt < 4; ++mt)
        #pragma unroll
        for (int r = 0; r < 4; ++r) {
            size_t row = (size_t)(bm + wm * 64 + mt * 16 + quad * 4 + r) * N;
            #pragma unroll
            for (int nt = 0; nt < 4; ++nt) {
                int col = bn + wn * 64 + nt * 16 + l15;
                C[row + col] = f2bf(acc[mt][nt][r] + bias[col]);
            }
        }
}

// ---------------- plain bf16 MFMA GEMM (fp32 out) ----------------
__global__ __launch_bounds__(256, 3) void gemm_bf16(
    const ushort_t* __restrict__ A, const ushort_t* __restrict__ B,
    const float* __restrict__ bias, float* __restrict__ C,
    int M, int N, int K)
{
    __shared__ ushort_t Ah[128][32], Bh[128][32];
    const int bn = blockIdx.x * 128, bm = blockIdx.y * 128;
    const int t = threadIdx.x, w = t >> 6, lane = t & 63;
    const int l15 = lane & 15, quad = lane >> 4;
    const int wm = w >> 1, wn = w & 1;

    const int srow = w * 32 + (lane >> 2);
    const int skp  = (lane & 3) ^ ((lane >> 2) & 3);
    const int scol = skp * 8;
    const ushort_t* ga = A + (size_t)(bm + srow) * K + scol;
    const ushort_t* gb = B + (size_t)(bn + srow) * K + scol;
    const size_t rstep = (size_t)16 * K;
    const int fcol = ((quad ^ (l15 & 3)) * 8);

    floatx4 acc[4][4];
    #pragma unroll
    for (int mt = 0; mt < 4; ++mt)
        #pragma unroll
        for (int nt = 0; nt < 4; ++nt) acc[mt][nt] = (floatx4){0.f, 0.f, 0.f, 0.f};

    for (int k0 = 0; k0 < K; k0 += 32) {
        #pragma unroll
        for (int i = 0; i < 2; ++i) {
            gload16(ga + i * rstep + k0, &Ah[w * 32 + i * 16][0]);
            gload16(gb + i * rstep + k0, &Bh[w * 32 + i * 16][0]);
        }
        __syncthreads();
        short8 ah[4], bh[4];
        #pragma unroll
        for (int x = 0; x < 4; ++x) {
            ah[x] = *(const short8*)&Ah[wm * 64 + x * 16 + l15][fcol];
            bh[x] = *(const short8*)&Bh[wn * 64 + x * 16 + l15][fcol];
        }
        #pragma unroll
        for (int mt = 0; mt < 4; ++mt)
            #pragma unroll
            for (int nt = 0; nt < 4; ++nt)
                acc[mt][nt] = __builtin_amdgcn_mfma_f32_16x16x32_bf16(ah[mt], bh[nt], acc[mt][nt], 0, 0, 0);
        __syncthreads();
    }
    #pragma unroll
    for (int mt = 0; mt < 4; ++mt)
        #pragma unroll
        for (int r = 0; r < 4; ++r) {
            size_t row = (size_t)(bm + wm * 64 + mt * 16 + quad * 4 + r) * N;
            #pragma unroll
            for (int nt = 0; nt < 4; ++nt) {
                int col = bn + wn * 64 + nt * 16 + l15;
                C[row + col] = acc[mt][nt][r] + bias[col];
            }
        }
}

// ---------------- MFMA flash attention v3 ----------------
// S^T formulation (validated R5). K and pre-transposed V staged via
// global_load_lds width=16 into unpadded [64][64] LDS tiles with an XOR
// chunk swizzle baked into the per-lane GLOBAL address (gload's LDS dest is
// fixed base+lane*16). Zero staging VALU.
__global__ __launch_bounds__(256, 2) void flash_v3(
    const ushort_t* __restrict__ qkv, const ushort_t* __restrict__ vtg,
    const int* __restrict__ mask, ushort_t* __restrict__ attn, int S)
{
    __shared__ ushort_t Ks[64][64];          // [key][dchunk^ (key&7)]
    __shared__ ushort_t Vt[64][64];          // [d][keychunk ^ (d&7)]
    __shared__ ushort_t Ps[4][16][72];       // per-wave P^T: [q(16)][key(64)]
    __shared__ float Madd[64];

    const int b = blockIdx.z, h = blockIdx.y, q0 = blockIdx.x * 128;
    const int t = threadIdx.x, wave = t >> 6, lane = t & 63;
    const int l15 = lane & 15, quad = lane >> 4;
    const size_t bS = (size_t)b * S;
    const float c1  = 0.125f * 1.44269504088896340736f;  // (1/sqrt(D))*log2(e)
    const float OFF = 24.0f;

    short8 qf[2][2];
    #pragma unroll
    for (int tt = 0; tt < 2; ++tt) {
        int q = q0 + wave * 32 + tt * 16 + l15;
        const ushort_t* qp = qkv + (bS + q) * 3072 + h * 64;
        qf[tt][0] = *(const short8*)(qp + quad * 8);
        qf[tt][1] = *(const short8*)(qp + 32 + quad * 8);
    }

    // staging addresses: wave covers rows [wave*16, wave*16+16), instr i adds 8
    const int srow  = wave * 16 + (lane >> 3);                 // row (key or d)
    const int schnk = ((lane & 7) ^ ((lane >> 3) & 7)) * 8;    // swizzled chunk
    const ushort_t* gK = qkv + (bS + srow) * 3072 + 1024 + h * 64 + schnk;
    const ushort_t* gV = vtg + ((size_t)(b * 16 + h) * 64 + srow) * 2048 + schnk;

    floatx4 outacc[2][4];
    float lsum[2] = {0.f, 0.f};
    #pragma unroll
    for (int tt = 0; tt < 2; ++tt)
        #pragma unroll
        for (int dt = 0; dt < 4; ++dt) outacc[tt][dt] = (floatx4){0.f, 0.f, 0.f, 0.f};

    for (int k0 = 0; k0 < S; k0 += 64) {
        gload16(gK + (size_t)k0 * 3072,              &Ks[wave * 16][0]);
        gload16(gK + (size_t)k0 * 3072 + 8 * 3072,   &Ks[wave * 16 + 8][0]);
        gload16(gV + k0,                             &Vt[wave * 16][0]);
        gload16(gV + k0 + 8 * 2048,                  &Vt[wave * 16 + 8][0]);
        if (t < 64) Madd[t] = (mask[bS + k0 + t] ? 0.f : -1e30f) - OFF;
        __syncthreads();

        // fragment loads with XOR deswizzle (row&7 == l15&7 for both tiles)
        short8 kf[2][4], vf[2][4];
        #pragma unroll
        for (int kc = 0; kc < 2; ++kc)
            #pragma unroll
            for (int c = 0; c < 4; ++c) {
                int ch = ((kc * 4 + quad) ^ (l15 & 7)) * 8;
                kf[kc][c] = *(const short8*)&Ks[c * 16 + l15][ch];
                vf[kc][c] = *(const short8*)&Vt[c * 16 + l15][ch];
            }
        float4 madd4[4];
        #pragma unroll
        for (int c = 0; c < 4; ++c) madd4[c] = *(const float4*)&Madd[c * 16 + quad * 4];

        #pragma unroll
        for (int tt = 0; tt < 2; ++tt) {
            // S^T: lane holds keys c*16+quad*4+r for query q = l15
            floatx4 sc[4];
            #pragma unroll
            for (int c = 0; c < 4; ++c) {
                sc[c] = (floatx4){0.f, 0.f, 0.f, 0.f};
                sc[c] = __builtin_amdgcn_mfma_f32_16x16x32_bf16(kf[0][c], qf[tt][0], sc[c], 0, 0, 0);
                sc[c] = __builtin_amdgcn_mfma_f32_16x16x32_bf16(kf[1][c], qf[tt][1], sc[c], 0, 0, 0);
            }
            // p = exp2(s*c1 + madd); pack consecutive-key quads; one b64 per c
            #pragma unroll
            for (int c = 0; c < 4; ++c) {
                float p0 = hexp2(fmaf(sc[c][0], c1, madd4[c].x));
                float p1 = hexp2(fmaf(sc[c][1], c1, madd4[c].y));
                float p2 = hexp2(fmaf(sc[c][2], c1, madd4[c].z));
                float p3 = hexp2(fmaf(sc[c][3], c1, madd4[c].w));
                lsum[tt] += (p0 + p1) + (p2 + p3);
                uint2 pk;
                pk.x = (unsigned)f2bf(p0) | ((unsigned)f2bf(p1) << 16);
                pk.y = (unsigned)f2bf(p2) | ((unsigned)f2bf(p3) << 16);
                *(uint2*)&Ps[wave][l15][c * 16 + quad * 4] = pk;
            }
            short8 pf0 = *(const short8*)&Ps[wave][l15][quad * 8];
            short8 pf1 = *(const short8*)&Ps[wave][l15][32 + quad * 8];
            // out^T += V^T * P^T : lane holds (d = dt*16+quad*4+r, q = l15)
            #pragma unroll
            for (int dt = 0; dt < 4; ++dt) {
                outacc[tt][dt] = __builtin_amdgcn_mfma_f32_16x16x32_bf16(vf[0][dt], pf0, outacc[tt][dt], 0, 0, 0);
                outacc[tt][dt] = __builtin_amdgcn_mfma_f32_16x16x32_bf16(vf[1][dt], pf1, outacc[tt][dt], 0, 0, 0);
            }
        }
        __syncthreads();
    }

    // l: sum across the 4 quads (each quad covered a disjoint key subset)
    #pragma unroll
    for (int tt = 0; tt < 2; ++tt) {
        lsum[tt] += __shfl_xor(lsum[tt], 16);
        lsum[tt] += __shfl_xor(lsum[tt], 32);
    }

    #pragma unroll
    for (int tt = 0; tt < 2; ++tt) {
        float inv = 1.f / lsum[tt];
        int q = q0 + wave * 32 + tt * 16 + l15;
        ushort_t* orow = attn + (bS + q) * 1024 + h * 64;
        #pragma unroll
        for (int dt = 0; dt < 4; ++dt) {
            uint2 pk;
            pk.x = (unsigned)f2bf(outacc[tt][dt][0] * inv) |
                   ((unsigned)f2bf(outacc[tt][dt][1] * inv) << 16);
            pk.y = (unsigned)f2bf(outacc[tt][dt][2] * inv) |
                   ((unsigned)f2bf(outacc[tt][dt][3] * inv) << 16);
            *(uint2*)&orow[dt * 16 + quad * 4] = pk;
        }
    }
}

extern "C" void kernel_launch(void* const* d_in, const int* in_sizes, int n_in,
                              void* d_out, int out_size, void* d_ws, size_t ws_size,
                              hipStream_t stream) {
    const float* x    = (const float*)d_in[0];   // (2,2048,1024)
    const int*   mask = (const int*)  d_in[1];   // (2,2048)
    const float* Wqkv = (const float*)d_in[2];   // (1024,3072)
    const float* bqkv = (const float*)d_in[3];   // (3072,)
    const float* Wout = (const float*)d_in[4];   // (1024,1024)
    const float* bout = (const float*)d_in[5];   // (1024,)
    float* out = (float*)d_out;                  // (2,2048,1024) fp32

    char* ws = (char*)d_ws;
    ushort_t* xhi  = (ushort_t*)(ws);                          //  8 MB  4096x1024
    ushort_t* xlo  = (ushort_t*)(ws + 8388608);                //  8 MB
    ushort_t* wqT  = (ushort_t*)(ws + 16777216);               //  6 MB  3072x1024
    ushort_t* qkvb = (ushort_t*)(ws + 23068672);               // 24 MB  4096x3072
    ushort_t* attnb= (ushort_t*)(ws + 48234496);               //  8 MB  4096x1024
    ushort_t* woT  = (ushort_t*)(ws + 56623104);               //  2 MB  1024x1024
    ushort_t* vtg  = (ushort_t*)(ws + 58720256);               //  8 MB  2x16x64x2048

    const int M = 4096, E = 1024, N3 = 3072, S = 2048;

    conv_split<<<dim3(M * E / 1024), dim3(256), 0, stream>>>(x, xhi, xlo);
    conv_T_hi<<<dim3(N3 / 32, E / 32), dim3(256), 0, stream>>>(Wqkv, wqT, E, N3);

    gemm_split2<<<dim3(N3 / 128, M / 128), dim3(256), 0, stream>>>(
        xhi, xlo, wqT, bqkv, qkvb, M, N3, E);

    transpose_v<<<dim3(S / 64, 16, 2), dim3(256), 0, stream>>>(qkvb, vtg);

    flash_v3<<<dim3(S / 128, 16, 2), dim3(256), 0, stream>>>(qkvb, vtg, mask, attnb, S);

    conv_T_hi<<<dim3(E / 32, E / 32), dim3(256), 0, stream>>>(Wout, woT, E, E);

    gemm_bf16<<<dim3(E / 128, M / 128), dim3(256), 0, stream>>>(
        attnb, woT, bout, out, M, E, E);
}

// Round 7
// 210.280 us; speedup vs baseline: 7.6115x; 1.0914x over previous
//
#include <hip/hip_runtime.h>

// B=2, S=2048, E=1024, H=16, D=64; rows = B*S = 4096; 3E = 3072.

typedef __attribute__((ext_vector_type(8))) short short8;     // 8 bf16 (A/B frag)
typedef __attribute__((ext_vector_type(4))) float floatx4;    // C/D frag
typedef unsigned short ushort_t;

static __device__ __forceinline__ ushort_t f2bf(float f) {
    unsigned u = __float_as_uint(f);
    u += 0x7fffu + ((u >> 16) & 1u);      // round-to-nearest-even
    return (ushort_t)(u >> 16);
}
// pack two fp32 -> bf16x2 (RNE); single v_cvt_pk_bf16_f32 when available
#if __has_builtin(__builtin_amdgcn_cvt_pk_bf16_f32)
typedef __attribute__((ext_vector_type(2))) __bf16 bf16x2_t;
static __device__ __forceinline__ unsigned pack2bf(float a, float b) {
    bf16x2_t r = __builtin_amdgcn_cvt_pk_bf16_f32(a, b);
    return __builtin_bit_cast(unsigned, r);
}
#else
static __device__ __forceinline__ unsigned pack2bf(float a, float b) {
    return (unsigned)f2bf(a) | ((unsigned)f2bf(b) << 16);
}
#endif
static __device__ __forceinline__ float hexp2(float x) {
    return __builtin_amdgcn_exp2f(x);
}
// async global->LDS, 16B per lane; LDS dest = wave-uniform base + lane*16
static __device__ __forceinline__ void gload16(const void* g, void* l) {
    __builtin_amdgcn_global_load_lds(
        (const __attribute__((address_space(1))) unsigned int*)g,
        (__attribute__((address_space(3))) unsigned int*)l, 16, 0, 0);
}

// ---------------- conversion kernels ----------------
// fp32 -> bf16 (RNE), float4 per thread
__global__ __launch_bounds__(256) void conv_hi(const float* __restrict__ in,
                                               ushort_t* __restrict__ out) {
    int i = blockIdx.x * 256 + threadIdx.x;
    float4 v = ((const float4*)in)[i];
    uint2 o;
    o.x = pack2bf(v.x, v.y);
    o.y = pack2bf(v.z, v.w);
    ((uint2*)out)[i] = o;
}

// W[K,N] fp32 -> WT[N,K] bf16 (transpose), 32x32 LDS tiles
__global__ __launch_bounds__(256) void conv_T_hi(const float* __restrict__ W,
                                                 ushort_t* __restrict__ hiT,
                                                 int K, int N) {
    __shared__ float tile[32][33];
    const int nb = blockIdx.x * 32, kb = blockIdx.y * 32;
    const int t = threadIdx.x;
    const int r = t >> 3, c4 = (t & 7) * 4;
    float4 v = *(const float4*)&W[(size_t)(kb + r) * N + nb + c4];
    tile[r][c4 + 0] = v.x; tile[r][c4 + 1] = v.y;
    tile[r][c4 + 2] = v.z; tile[r][c4 + 3] = v.w;
    __syncthreads();
    uint2 o;
    o.x = pack2bf(tile[c4 + 0][r], tile[c4 + 1][r]);
    o.y = pack2bf(tile[c4 + 2][r], tile[c4 + 3][r]);
    size_t off = ((size_t)(nb + r) * K + kb + c4) >> 2;   // uint2 index
    ((uint2*)hiT)[off] = o;
}

// V part of qkvb -> Vtg[b][h][d][s]  (64x64 tiles through LDS)
__global__ __launch_bounds__(256) void transpose_v(const ushort_t* __restrict__ qkvb,
                                                   ushort_t* __restrict__ vtg) {
    __shared__ ushort_t tile[64][72];
    const int b = blockIdx.z, h = blockIdx.y, s0 = blockIdx.x * 64;
    const int t = threadIdx.x;
    #pragma unroll
    for (int p = 0; p < 2; ++p) {
        int idx = t + p * 256;
        int sl = idx >> 3, dc = (idx & 7) * 8;
        *(uint4*)&tile[sl][dc] =
            *(const uint4*)&qkvb[(size_t)(b * 2048 + s0 + sl) * 3072 + 2048 + h * 64 + dc];
    }
    __syncthreads();
    #pragma unroll
    for (int p = 0; p < 2; ++p) {
        int idx = t + p * 256;
        int dl = idx >> 3, sc = (idx & 7) * 8;
        ushort_t v[8];
        #pragma unroll
        for (int j = 0; j < 8; ++j) v[j] = tile[sc + j][dl];
        *(uint4*)&vtg[(size_t)((b * 16 + h) * 64 + dl) * 2048 + s0 + sc] = *(const uint4*)v;
    }
}

// ---------------- plain bf16 MFMA GEMM, bf16 output ----------------
// C_bf16[M,N] = A[M,K] @ B^T[N,K]^T + bias. 128x128 tile, BK=32, 4 waves.
__global__ __launch_bounds__(256, 3) void gemm_bf16_bf(
    const ushort_t* __restrict__ A, const ushort_t* __restrict__ B,
    const float* __restrict__ bias, ushort_t* __restrict__ C,
    int M, int N, int K)
{
    __shared__ ushort_t Ah[128][32], Bh[128][32];
    const int bn = blockIdx.x * 128, bm = blockIdx.y * 128;
    const int t = threadIdx.x, w = t >> 6, lane = t & 63;
    const int l15 = lane & 15, quad = lane >> 4;
    const int wm = w >> 1, wn = w & 1;

    const int srow = w * 32 + (lane >> 2);
    const int skp  = (lane & 3) ^ ((lane >> 2) & 3);     // swizzled global k-part
    const int scol = skp * 8;
    const ushort_t* ga = A + (size_t)(bm + srow) * K + scol;
    const ushort_t* gb = B + (size_t)(bn + srow) * K + scol;
    const size_t rstep = (size_t)16 * K;
    const int fcol = ((quad ^ (l15 & 3)) * 8);           // frag read col (deswizzle)

    floatx4 acc[4][4];
    #pragma unroll
    for (int mt = 0; mt < 4; ++mt)
        #pragma unroll
        for (int nt = 0; nt < 4; ++nt) acc[mt][nt] = (floatx4){0.f, 0.f, 0.f, 0.f};

    for (int k0 = 0; k0 < K; k0 += 32) {
        #pragma unroll
        for (int i = 0; i < 2; ++i) {
            gload16(ga + i * rstep + k0, &Ah[w * 32 + i * 16][0]);
            gload16(gb + i * rstep + k0, &Bh[w * 32 + i * 16][0]);
        }
        __syncthreads();
        short8 ah[4], bh[4];
        #pragma unroll
        for (int x = 0; x < 4; ++x) {
            ah[x] = *(const short8*)&Ah[wm * 64 + x * 16 + l15][fcol];
            bh[x] = *(const short8*)&Bh[wn * 64 + x * 16 + l15][fcol];
        }
        #pragma unroll
        for (int mt = 0; mt < 4; ++mt)
            #pragma unroll
            for (int nt = 0; nt < 4; ++nt)
                acc[mt][nt] = __builtin_amdgcn_mfma_f32_16x16x32_bf16(ah[mt], bh[nt], acc[mt][nt], 0, 0, 0);
        __syncthreads();
    }
    #pragma unroll
    for (int mt = 0; mt < 4; ++mt)
        #pragma unroll
        for (int r = 0; r < 4; ++r) {
            size_t row = (size_t)(bm + wm * 64 + mt * 16 + quad * 4 + r) * N;
            #pragma unroll
            for (int nt = 0; nt < 4; ++nt) {
                int col = bn + wn * 64 + nt * 16 + l15;
                C[row + col] = f2bf(acc[mt][nt][r] + bias[col]);
            }
        }
}

// ---------------- plain bf16 MFMA GEMM, fp32 output ----------------
__global__ __launch_bounds__(256, 3) void gemm_bf16_f32(
    const ushort_t* __restrict__ A, const ushort_t* __restrict__ B,
    const float* __restrict__ bias, float* __restrict__ C,
    int M, int N, int K)
{
    __shared__ ushort_t Ah[128][32], Bh[128][32];
    const int bn = blockIdx.x * 128, bm = blockIdx.y * 128;
    const int t = threadIdx.x, w = t >> 6, lane = t & 63;
    const int l15 = lane & 15, quad = lane >> 4;
    const int wm = w >> 1, wn = w & 1;

    const int srow = w * 32 + (lane >> 2);
    const int skp  = (lane & 3) ^ ((lane >> 2) & 3);
    const int scol = skp * 8;
    const ushort_t* ga = A + (size_t)(bm + srow) * K + scol;
    const ushort_t* gb = B + (size_t)(bn + srow) * K + scol;
    const size_t rstep = (size_t)16 * K;
    const int fcol = ((quad ^ (l15 & 3)) * 8);

    floatx4 acc[4][4];
    #pragma unroll
    for (int mt = 0; mt < 4; ++mt)
        #pragma unroll
        for (int nt = 0; nt < 4; ++nt) acc[mt][nt] = (floatx4){0.f, 0.f, 0.f, 0.f};

    for (int k0 = 0; k0 < K; k0 += 32) {
        #pragma unroll
        for (int i = 0; i < 2; ++i) {
            gload16(ga + i * rstep + k0, &Ah[w * 32 + i * 16][0]);
            gload16(gb + i * rstep + k0, &Bh[w * 32 + i * 16][0]);
        }
        __syncthreads();
        short8 ah[4], bh[4];
        #pragma unroll
        for (int x = 0; x < 4; ++x) {
            ah[x] = *(const short8*)&Ah[wm * 64 + x * 16 + l15][fcol];
            bh[x] = *(const short8*)&Bh[wn * 64 + x * 16 + l15][fcol];
        }
        #pragma unroll
        for (int mt = 0; mt < 4; ++mt)
            #pragma unroll
            for (int nt = 0; nt < 4; ++nt)
                acc[mt][nt] = __builtin_amdgcn_mfma_f32_16x16x32_bf16(ah[mt], bh[nt], acc[mt][nt], 0, 0, 0);
        __syncthreads();
    }
    #pragma unroll
    for (int mt = 0; mt < 4; ++mt)
        #pragma unroll
        for (int r = 0; r < 4; ++r) {
            size_t row = (size_t)(bm + wm * 64 + mt * 16 + quad * 4 + r) * N;
            #pragma unroll
            for (int nt = 0; nt < 4; ++nt) {
                int col = bn + wn * 64 + nt * 16 + l15;
                C[row + col] = acc[mt][nt][r] + bias[col];
            }
        }
}

// ---------------- MFMA flash attention v4 ----------------
// 64 queries/block (16/wave), grid 1024 = 4 blocks/CU. S^T formulation
// (validated R5/R6). K and pre-transposed V staged via global_load_lds
// width=16 into unpadded [64][64] tiles, XOR chunk swizzle on the global
// address. XCD-aware block swizzle: all 32 q-blocks of one (b,h) share an XCD.
__global__ __launch_bounds__(256, 4) void flash_v4(
    const ushort_t* __restrict__ qkv, const ushort_t* __restrict__ vtg,
    const int* __restrict__ mask, ushort_t* __restrict__ attn, int S)
{
    __shared__ ushort_t Ks[64][64];          // [key][dchunk ^ (key&7)]
    __shared__ ushort_t Vt[64][64];          // [d][keychunk ^ (d&7)]
    __shared__ ushort_t Ps[4][16][72];       // per-wave P^T: [q(16)][key(64)]
    __shared__ float Madd[64];

    // block swizzle: xcd = blk&7 stays constant across a (b,h)'s 32 q-blocks
    const int blk = blockIdx.x;
    const int xcd = blk & 7, rr = blk >> 3;
    const int qi = rr & 31, gg = xcd + 8 * (rr >> 5);    // gg in [0,32)
    const int b = gg >> 4, h = gg & 15, q0 = qi * 64;

    const int t = threadIdx.x, wave = t >> 6, lane = t & 63;
    const int l15 = lane & 15, quad = lane >> 4;
    const size_t bS = (size_t)b * S;
    const float c1  = 0.125f * 1.44269504088896340736f;  // (1/sqrt(D))*log2(e)
    const float OFF = 24.0f;

    // Q frags (B operand): lane l15 = query, chunk = quad
    short8 qf[2];
    {
        int q = q0 + wave * 16 + l15;
        const ushort_t* qp = qkv + (bS + q) * 3072 + h * 64;
        qf[0] = *(const short8*)(qp + quad * 8);
        qf[1] = *(const short8*)(qp + 32 + quad * 8);
    }

    // staging addresses: wave covers rows [wave*16, wave*16+16)
    const int srow  = wave * 16 + (lane >> 3);                 // row (key or d)
    const int schnk = ((lane & 7) ^ ((lane >> 3) & 7)) * 8;    // swizzled chunk
    const ushort_t* gK = qkv + (bS + srow) * 3072 + 1024 + h * 64 + schnk;
    const ushort_t* gV = vtg + ((size_t)(b * 16 + h) * 64 + srow) * 2048 + schnk;

    floatx4 outacc[4];
    float lsum = 0.f;
    #pragma unroll
    for (int dt = 0; dt < 4; ++dt) outacc[dt] = (floatx4){0.f, 0.f, 0.f, 0.f};

    for (int k0 = 0; k0 < S; k0 += 64) {
        gload16(gK + (size_t)k0 * 3072,             &Ks[wave * 16][0]);
        gload16(gK + (size_t)k0 * 3072 + 8 * 3072,  &Ks[wave * 16 + 8][0]);
        gload16(gV + k0,                            &Vt[wave * 16][0]);
        gload16(gV + k0 + 8 * 2048,                 &Vt[wave * 16 + 8][0]);
        if (t < 64) Madd[t] = (mask[bS + k0 + t] ? 0.f : -1e30f) - OFF;
        __syncthreads();

        // fragment loads with XOR deswizzle (row&7 == l15&7 for both tiles)
        short8 kf[2][4], vf[2][4];
        #pragma unroll
        for (int kc = 0; kc < 2; ++kc)
            #pragma unroll
            for (int c = 0; c < 4; ++c) {
                int ch = ((kc * 4 + quad) ^ (l15 & 7)) * 8;
                kf[kc][c] = *(const short8*)&Ks[c * 16 + l15][ch];
                vf[kc][c] = *(const short8*)&Vt[c * 16 + l15][ch];
            }
        float4 madd4[4];
        #pragma unroll
        for (int c = 0; c < 4; ++c) madd4[c] = *(const float4*)&Madd[c * 16 + quad * 4];

        // S^T: lane holds keys c*16+quad*4+r for query q = l15
        floatx4 sc[4];
        #pragma unroll
        for (int c = 0; c < 4; ++c) {
            sc[c] = (floatx4){0.f, 0.f, 0.f, 0.f};
            sc[c] = __builtin_amdgcn_mfma_f32_16x16x32_bf16(kf[0][c], qf[0], sc[c], 0, 0, 0);
            sc[c] = __builtin_amdgcn_mfma_f32_16x16x32_bf16(kf[1][c], qf[1], sc[c], 0, 0, 0);
        }
        // p = exp2(s*c1 + madd); one b64 Ps write per c
        #pragma unroll
        for (int c = 0; c < 4; ++c) {
            float p0 = hexp2(fmaf(sc[c][0], c1, madd4[c].x));
            float p1 = hexp2(fmaf(sc[c][1], c1, madd4[c].y));
            float p2 = hexp2(fmaf(sc[c][2], c1, madd4[c].z));
            float p3 = hexp2(fmaf(sc[c][3], c1, madd4[c].w));
            lsum += (p0 + p1) + (p2 + p3);
            uint2 pk;
            pk.x = pack2bf(p0, p1);
            pk.y = pack2bf(p2, p3);
            *(uint2*)&Ps[wave][l15][c * 16 + quad * 4] = pk;
        }
        short8 pf0 = *(const short8*)&Ps[wave][l15][quad * 8];
        short8 pf1 = *(const short8*)&Ps[wave][l15][32 + quad * 8];
        // out^T += V^T * P^T : lane holds (d = dt*16+quad*4+r, q = l15)
        #pragma unroll
        for (int dt = 0; dt < 4; ++dt) {
            outacc[dt] = __builtin_amdgcn_mfma_f32_16x16x32_bf16(vf[0][dt], pf0, outacc[dt], 0, 0, 0);
            outacc[dt] = __builtin_amdgcn_mfma_f32_16x16x32_bf16(vf[1][dt], pf1, outacc[dt], 0, 0, 0);
        }
        __syncthreads();
    }

    // l: sum across the 4 quads (each quad covered a disjoint key subset)
    lsum += __shfl_xor(lsum, 16);
    lsum += __shfl_xor(lsum, 32);

    {
        float inv = 1.f / lsum;
        int q = q0 + wave * 16 + l15;
        ushort_t* orow = attn + (bS + q) * 1024 + h * 64;
        #pragma unroll
        for (int dt = 0; dt < 4; ++dt) {
            uint2 pk;
            pk.x = pack2bf(outacc[dt][0] * inv, outacc[dt][1] * inv);
            pk.y = pack2bf(outacc[dt][2] * inv, outacc[dt][3] * inv);
            *(uint2*)&orow[dt * 16 + quad * 4] = pk;
        }
    }
}

extern "C" void kernel_launch(void* const* d_in, const int* in_sizes, int n_in,
                              void* d_out, int out_size, void* d_ws, size_t ws_size,
                              hipStream_t stream) {
    const float* x    = (const float*)d_in[0];   // (2,2048,1024)
    const int*   mask = (const int*)  d_in[1];   // (2,2048)
    const float* Wqkv = (const float*)d_in[2];   // (1024,3072)
    const float* bqkv = (const float*)d_in[3];   // (3072,)
    const float* Wout = (const float*)d_in[4];   // (1024,1024)
    const float* bout = (const float*)d_in[5];   // (1024,)
    float* out = (float*)d_out;                  // (2,2048,1024) fp32

    char* ws = (char*)d_ws;
    ushort_t* xb   = (ushort_t*)(ws);                          //  8 MB  4096x1024
    ushort_t* wqT  = (ushort_t*)(ws + 8388608);                //  6 MB  3072x1024
    ushort_t* qkvb = (ushort_t*)(ws + 14680064);               // 24 MB  4096x3072
    ushort_t* attnb= (ushort_t*)(ws + 39845888);               //  8 MB  4096x1024
    ushort_t* woT  = (ushort_t*)(ws + 48234496);               //  2 MB  1024x1024
    ushort_t* vtg  = (ushort_t*)(ws + 50331648);               //  8 MB  2x16x64x2048

    const int M = 4096, E = 1024, N3 = 3072, S = 2048;

    conv_hi<<<dim3(M * E / 1024), dim3(256), 0, stream>>>(x, xb);
    conv_T_hi<<<dim3(N3 / 32, E / 32), dim3(256), 0, stream>>>(Wqkv, wqT, E, N3);

    gemm_bf16_bf<<<dim3(N3 / 128, M / 128), dim3(256), 0, stream>>>(
        xb, wqT, bqkv, qkvb, M, N3, E);

    transpose_v<<<dim3(S / 64, 16, 2), dim3(256), 0, stream>>>(qkvb, vtg);

    flash_v4<<<dim3(1024), dim3(256), 0, stream>>>(qkvb, vtg, mask, attnb, S);

    conv_T_hi<<<dim3(E / 32, E / 32), dim3(256), 0, stream>>>(Wout, woT, E, E);

    gemm_bf16_f32<<<dim3(E / 128, M / 128), dim3(256), 0, stream>>>(
        attnb, woT, bout, out, M, E, E);
}